// Round 1
// baseline (288.324 us; speedup 1.0000x reference)
//
#include <hip/hip_runtime.h>
#include <math.h>

// CliffordDDIDecoder: out[b,r] = (1/8) * dot(w[b,0:64], Tflat[r,0:64])
//   m = proj(h) for perp/vuln; w from Clifford triple-product collapse.
// Round 1: correct-first fp32. GEMM1 (B x 512 x 256) dominates (~4.3 G-FMA).

#define B_ 16384
#define D_ 512
#define H_ 256
#define R_ 95

// ---------------- fused projection: x1=h@W1+b1 -> LN -> gelu -> m=x@W2+b2 ----
__global__ __launch_bounds__(256, 2)
void cdd_proj_kernel(const float* __restrict__ h_p, const float* __restrict__ h_v,
                     const float* __restrict__ Wp1, const float* __restrict__ bp1,
                     const float* __restrict__ lgp, const float* __restrict__ lbp,
                     const float* __restrict__ Wp2, const float* __restrict__ bp2,
                     const float* __restrict__ Wv1, const float* __restrict__ bv1,
                     const float* __restrict__ lgv, const float* __restrict__ lbv,
                     const float* __restrict__ Wv2, const float* __restrict__ bv2,
                     float* __restrict__ mp_out, float* __restrict__ mv_out)
{
    const int which = blockIdx.y;
    const float* __restrict__ h  = which ? h_v : h_p;
    const float* __restrict__ W1 = which ? Wv1 : Wp1;
    const float* __restrict__ b1 = which ? bv1 : bp1;
    const float* __restrict__ lg = which ? lgv : lgp;
    const float* __restrict__ lb = which ? lbv : lbp;
    const float* __restrict__ W2 = which ? Wv2 : Wp2;
    const float* __restrict__ b2 = which ? bv2 : bp2;
    float* __restrict__ mo = which ? mv_out : mp_out;

    // LDS: staging region (Ws[32][256] = 8192 + hsT[32][68] = 2176 floats)
    // is dead after GEMM1; xs[64][260] = 16640 floats aliases it. 66.6 KB.
    __shared__ float smem[64 * 260];
    float* Ws  = smem;               // [32][256]
    float* hsT = smem + 32 * 256;    // [32][68] (pad 68 keeps b128 align)
    float* xs  = smem;               // [64][260]

    const int t  = threadIdx.x;
    const int rt = t >> 5, ct = t & 31;
    const int r0 = rt * 8, c0 = ct * 8;    // 8x8 micro-tile
    const int b0 = blockIdx.x * 64;

    float acc[8][8];
#pragma unroll
    for (int i = 0; i < 8; ++i)
#pragma unroll
        for (int j = 0; j < 8; ++j) acc[i][j] = 0.f;

    const int hr = t >> 2, hk = (t & 3) * 8;   // h staging: row, k-offset

    for (int k0 = 0; k0 < D_; k0 += 32) {
        __syncthreads();
        // stage h tile (64 rows x 32 k), transposed into hsT[k][row]
        {
            const float4 hv0 = *(const float4*)(h + (size_t)(b0 + hr) * D_ + k0 + hk);
            const float4 hv1 = *(const float4*)(h + (size_t)(b0 + hr) * D_ + k0 + hk + 4);
            hsT[(hk + 0) * 68 + hr] = hv0.x;
            hsT[(hk + 1) * 68 + hr] = hv0.y;
            hsT[(hk + 2) * 68 + hr] = hv0.z;
            hsT[(hk + 3) * 68 + hr] = hv0.w;
            hsT[(hk + 4) * 68 + hr] = hv1.x;
            hsT[(hk + 5) * 68 + hr] = hv1.y;
            hsT[(hk + 6) * 68 + hr] = hv1.z;
            hsT[(hk + 7) * 68 + hr] = hv1.w;
        }
        // stage W1 tile (32 k x 256 cols): 2048 float4, 8 per thread
#pragma unroll
        for (int j = 0; j < 8; ++j) {
            const int s  = t + j * 256;
            const int kr = s >> 6, cc = (s & 63) << 2;
            *(float4*)(Ws + kr * 256 + cc) =
                *(const float4*)(W1 + (size_t)(k0 + kr) * H_ + cc);
        }
        __syncthreads();
#pragma unroll 8
        for (int kk = 0; kk < 32; ++kk) {
            const float4 a0 = *(const float4*)(hsT + kk * 68 + r0);
            const float4 a1 = *(const float4*)(hsT + kk * 68 + r0 + 4);
            const float4 w0 = *(const float4*)(Ws + kk * 256 + c0);
            const float4 w1 = *(const float4*)(Ws + kk * 256 + c0 + 4);
            float av[8] = {a0.x, a0.y, a0.z, a0.w, a1.x, a1.y, a1.z, a1.w};
            float wv[8] = {w0.x, w0.y, w0.z, w0.w, w1.x, w1.y, w1.z, w1.w};
#pragma unroll
            for (int i = 0; i < 8; ++i)
#pragma unroll
                for (int j = 0; j < 8; ++j)
                    acc[i][j] = fmaf(av[i], wv[j], acc[i][j]);
        }
    }

    // ---- bias + LayerNorm (rows live in 32 lanes: butterfly) + exact GELU ----
    {
        const float4 ba  = *(const float4*)(b1 + c0);
        const float4 bb4 = *(const float4*)(b1 + c0 + 4);
        const float4 ga  = *(const float4*)(lg + c0);
        const float4 gb4 = *(const float4*)(lg + c0 + 4);
        const float4 ea  = *(const float4*)(lb + c0);
        const float4 eb4 = *(const float4*)(lb + c0 + 4);
        float bb[8] = {ba.x, ba.y, ba.z, ba.w, bb4.x, bb4.y, bb4.z, bb4.w};
        float gg[8] = {ga.x, ga.y, ga.z, ga.w, gb4.x, gb4.y, gb4.z, gb4.w};
        float ee[8] = {ea.x, ea.y, ea.z, ea.w, eb4.x, eb4.y, eb4.z, eb4.w};

        float mean[8], rstd[8];
#pragma unroll
        for (int i = 0; i < 8; ++i) {
            float s1 = 0.f, s2 = 0.f;
#pragma unroll
            for (int j = 0; j < 8; ++j) {
                acc[i][j] += bb[j];
                s1 += acc[i][j];
                s2 += acc[i][j] * acc[i][j];
            }
#pragma unroll
            for (int m = 16; m >= 1; m >>= 1) {
                s1 += __shfl_xor(s1, m, 64);
                s2 += __shfl_xor(s2, m, 64);
            }
            mean[i] = s1 * (1.f / 256.f);
            const float var = s2 * (1.f / 256.f) - mean[i] * mean[i];
            rstd[i] = rsqrtf(var + 1e-5f);
        }
        __syncthreads();   // all staging reads done -> safe to overwrite with xs
#pragma unroll
        for (int i = 0; i < 8; ++i) {
            float y[8];
#pragma unroll
            for (int j = 0; j < 8; ++j) {
                float x = (acc[i][j] - mean[i]) * rstd[i] * gg[j] + ee[j];
                y[j] = 0.5f * x * (1.f + erff(x * 0.70710678118654752f));
            }
            *(float4*)(xs + (r0 + i) * 260 + c0)     = make_float4(y[0], y[1], y[2], y[3]);
            *(float4*)(xs + (r0 + i) * 260 + c0 + 4) = make_float4(y[4], y[5], y[6], y[7]);
        }
    }
    __syncthreads();

    // ---- GEMM2: m[64][64] = xs[64][256] @ W2[256][64] + b2  (4x4 micro) ----
    {
        const int ct2 = t & 15, rt2 = t >> 4;
        const int cb = ct2 * 4, rb = rt2 * 4;
        const float4 b2v = *(const float4*)(b2 + cb);
        float a2[4][4];
#pragma unroll
        for (int i = 0; i < 4; ++i) {
            a2[i][0] = b2v.x; a2[i][1] = b2v.y; a2[i][2] = b2v.z; a2[i][3] = b2v.w;
        }
#pragma unroll 4
        for (int k = 0; k < H_; k += 4) {
            float xv[4][4];
#pragma unroll
            for (int i = 0; i < 4; ++i) {
                const float4 x4 = *(const float4*)(xs + (rb + i) * 260 + k);
                xv[i][0] = x4.x; xv[i][1] = x4.y; xv[i][2] = x4.z; xv[i][3] = x4.w;
            }
#pragma unroll
            for (int j = 0; j < 4; ++j) {
                const float4 wr = *(const float4*)(W2 + (size_t)(k + j) * 64 + cb);
                float wc[4] = {wr.x, wr.y, wr.z, wr.w};
#pragma unroll
                for (int i = 0; i < 4; ++i)
#pragma unroll
                    for (int c = 0; c < 4; ++c)
                        a2[i][c] = fmaf(xv[i][j], wc[c], a2[i][c]);
            }
        }
#pragma unroll
        for (int i = 0; i < 4; ++i)
            *(float4*)(mo + (size_t)(b0 + rb + i) * 64 + cb) =
                make_float4(a2[i][0], a2[i][1], a2[i][2], a2[i][3]);
    }
}

// ------------- Clifford collapse + readout: out[b,r] = dot(w[b], T[r]) / 8 ----
__global__ __launch_bounds__(256)
void cdd_cliff_kernel(const float* __restrict__ mp, const float* __restrict__ mv,
                      const float* __restrict__ T, const float* __restrict__ gw,
                      float* __restrict__ out)
{
    __shared__ float wfl[32 * 68];
    const int t   = threadIdx.x;
    const int b0  = blockIdx.x * 32;
    const int row = t >> 3, kq = t & 7;

    float g[8];
#pragma unroll
    for (int i = 0; i < 8; ++i) g[i] = gw[i];

    const float* mpp = mp + (size_t)(b0 + row) * 64 + kq * 8;
    const float* mvp = mv + (size_t)(b0 + row) * 64 + kq * 8;
    const float4 p0 = *(const float4*)(mpp), p1 = *(const float4*)(mpp + 4);
    const float4 q0 = *(const float4*)(mvp), q1 = *(const float4*)(mvp + 4);
    float mpv[8] = {p0.x, p0.y, p0.z, p0.w, p1.x, p1.y, p1.z, p1.w};
    float mvv[8] = {q0.x, q0.y, q0.z, q0.w, q1.x, q1.y, q1.z, q1.w};

    // basis order [1,e1,e2,e3,e12,e13,e23,e123]; idx<->mask table is self-inverse
    constexpr int MSK[8] = {0, 1, 2, 4, 3, 5, 6, 7};

    // v[m] = sum_j sign(m,j) * gw[idx(m^j)] * mv[j]   (G @ mv)
    float v[8];
#pragma unroll
    for (int m = 0; m < 8; ++m) {
        float s = 0.f;
#pragma unroll
        for (int j = 0; j < 8; ++j) {
            const int am = MSK[m], bm = MSK[j];
            const int par = (__popc((am >> 1) & bm) + __popc((am >> 2) & bm)) & 1;
            const float sg = par ? -1.f : 1.f;
            s = fmaf(sg * g[MSK[am ^ bm]], mvv[j], s);
        }
        v[m] = s;
    }
    // w[l] = sum_i mp[i] * sign(i,l) * v[idx(i^l)]
#pragma unroll
    for (int l = 0; l < 8; ++l) {
        float s = 0.f;
#pragma unroll
        for (int i = 0; i < 8; ++i) {
            const int am = MSK[i], bm = MSK[l];
            const int par = (__popc((am >> 1) & bm) + __popc((am >> 2) & bm)) & 1;
            const float sg = par ? -1.f : 1.f;
            s = fmaf(sg * mpv[i], v[MSK[am ^ bm]], s);
        }
        wfl[row * 68 + kq * 8 + l] = s;
    }
    __syncthreads();

    for (int idx = t; idx < 32 * 95; idx += 256) {
        const int rr = idx / 95;
        const int r  = idx - rr * 95;
        const float* wrow = wfl + rr * 68;
        const float* trow = T + r * 64;
        float s = 0.f;
#pragma unroll
        for (int c = 0; c < 64; c += 4) {
            const float4 wv = *(const float4*)(wrow + c);
            const float4 tv = *(const float4*)(trow + c);
            s += wv.x * tv.x + wv.y * tv.y + wv.z * tv.z + wv.w * tv.w;
        }
        out[(size_t)(b0 + rr) * 95 + r] = 0.125f * s;
    }
}

extern "C" void kernel_launch(void* const* d_in, const int* in_sizes, int n_in,
                              void* d_out, int out_size, void* d_ws, size_t ws_size,
                              hipStream_t stream)
{
    const float* h_p = (const float*)d_in[0];
    const float* h_v = (const float*)d_in[1];
    const float* Wp1 = (const float*)d_in[2];
    const float* bp1 = (const float*)d_in[3];
    const float* lgp = (const float*)d_in[4];
    const float* lbp = (const float*)d_in[5];
    const float* Wp2 = (const float*)d_in[6];
    const float* bp2 = (const float*)d_in[7];
    const float* Wv1 = (const float*)d_in[8];
    const float* bv1 = (const float*)d_in[9];
    const float* lgv = (const float*)d_in[10];
    const float* lbv = (const float*)d_in[11];
    const float* Wv2 = (const float*)d_in[12];
    const float* bv2 = (const float*)d_in[13];
    const float* T   = (const float*)d_in[14];
    const float* gw  = (const float*)d_in[15];
    float* out = (float*)d_out;

    float* mp = (float*)d_ws;                 // (B,64) fp32
    float* mv = mp + (size_t)B_ * 64;         // (B,64) fp32  (8.4 MB total)

    dim3 g1(B_ / 64, 2), blk(256);
    cdd_proj_kernel<<<g1, blk, 0, stream>>>(h_p, h_v, Wp1, bp1, lgp, lbp, Wp2, bp2,
                                            Wv1, bv1, lgv, lbv, Wv2, bv2, mp, mv);
    cdd_cliff_kernel<<<B_ / 32, 256, 0, stream>>>(mp, mv, T, gw, out);
}

// Round 4
// 162.966 us; speedup vs baseline: 1.7692x; 1.7692x over previous
//
#include <hip/hip_runtime.h>
#include <math.h>

// CliffordDDIDecoder — R4: retreat to R1's harness-proven two-kernel skeleton
// (proj -> m in ws -> cliff -> out), with R2's numerically-proven MFMA math
// inside the proj kernel. All kernels __launch_bounds__(256,2): every
// first-launch-correct config so far used (256,2); the (256,3) build was
// first-launch-wrong. m handoff stored bf16 so ws use (4.8 MB) < R1's proven
// 8.4 MB. Cliff kernel = R1's proven collapse + T staged in LDS (fixes R1's
// 129 us global-T access pattern).

#define B_ 16384
#define D_ 512
#define H_ 256
#define R_ 95

typedef __attribute__((ext_vector_type(8))) short short8;   // 8 bf16
typedef __attribute__((ext_vector_type(4))) float f32x4;

#define MFMA(a, b, c) __builtin_amdgcn_mfma_f32_16x16x32_bf16(a, b, c, 0, 0, 0)

__device__ __forceinline__ short f2bf(float x) {            // fp32 -> bf16 RNE
    union { float f; unsigned u; } v; v.f = x;
    unsigned r = v.u + 0x7fffu + ((v.u >> 16) & 1u);
    return (short)(r >> 16);
}
__device__ __forceinline__ float bf2f(short s) {
    union { float f; unsigned u; } v;
    v.u = ((unsigned)(unsigned short)s) << 16;
    return v.f;
}

// ---- prep: W1 -> [16 chunk][256 n][32 k] bf16 ; W2 -> [64 n][256 k] bf16 ----
__global__ __launch_bounds__(256)
void cdd_prep_kernel(const float* __restrict__ Wp1, const float* __restrict__ Wv1,
                     const float* __restrict__ Wp2, const float* __restrict__ Wv2,
                     short* __restrict__ W1c_p, short* __restrict__ W1c_v,
                     short* __restrict__ W2t_p, short* __restrict__ W2t_v)
{
    const int o = blockIdx.x * 256 + threadIdx.x;
    if (o < 16 * 256 * 32) {            // n-fast: coalesced W1 reads
        const int n = o & 255, kin = (o >> 8) & 31, ch = o >> 13;
        const int src = (ch * 32 + kin) * 256 + n;
        const int dst = ch * 8192 + n * 32 + kin;
        W1c_p[dst] = f2bf(Wp1[src]);
        W1c_v[dst] = f2bf(Wv1[src]);
    }
    if (o < 64 * 256) {
        const int n = o >> 8, k = o & 255;
        W2t_p[o] = f2bf(Wp2[k * 64 + n]);
        W2t_v[o] = f2bf(Wv2[k * 64 + n]);
    }
}

// ---- proj: x1=h@W1+b1 -> LN -> exact GELU -> m=x@W2+b2 (bf16 to ws) --------
// grid (512, 2): blockIdx.y picks perp/vuln (R1-proven decomposition).
__global__ __launch_bounds__(256, 2)
void cdd_proj_kernel(const float* __restrict__ h_p, const float* __restrict__ h_v,
                     const float* __restrict__ bp1, const float* __restrict__ lgp,
                     const float* __restrict__ lbp, const float* __restrict__ bp2,
                     const float* __restrict__ bv1, const float* __restrict__ lgv,
                     const float* __restrict__ lbv, const float* __restrict__ bv2,
                     const short* __restrict__ W1c_p, const short* __restrict__ W1c_v,
                     const short* __restrict__ W2t_p, const short* __restrict__ W2t_v,
                     short* __restrict__ mp_out, short* __restrict__ mv_out)
{
    __shared__ __align__(16) short hs[32 * 40];     // h chunk, bf16
    __shared__ __align__(16) short xs[32 * 264];    // gelu(LN(x1)), bf16
    __shared__ __align__(16) float lnbuf[256];      // per-wave LN partials

    const int which = blockIdx.y;
    const float* __restrict__ h   = which ? h_v : h_p;
    const float* __restrict__ b1  = which ? bv1 : bp1;
    const float* __restrict__ lg  = which ? lgv : lgp;
    const float* __restrict__ lb  = which ? lbv : lbp;
    const float* __restrict__ b2  = which ? bv2 : bp2;
    const short* __restrict__ W1c = which ? W1c_v : W1c_p;
    const short* __restrict__ W2t = which ? W2t_v : W2t_p;
    short* __restrict__ mo = which ? mv_out : mp_out;

    const int t = threadIdx.x;
    const int w = t >> 6, l = t & 63, q = l >> 4, c = l & 15;
    const int b0 = blockIdx.x * 32;
    const int hrow = t >> 3, hk = (t & 7) * 4;     // h staging map

    // ---------------- GEMM1: acc1[mt][nt] = h(32x512) @ W1(512x256) --------
    // wave w owns cols [64w, 64w+64); m-tiles 0..1 (all 32 rows).
    f32x4 acc1[2][4];
#pragma unroll
    for (int mt = 0; mt < 2; ++mt)
#pragma unroll
        for (int nt = 0; nt < 4; ++nt) acc1[mt][nt] = 0;

    const size_t hoff = (size_t)(b0 + hrow) * D_ + hk;
    const short* Wb0 = W1c + (w * 64 + c) * 32 + q * 8;

    for (int ch = 0; ch < 16; ++ch) {
        const float4 hv = *(const float4*)(h + hoff + ch * 32);
        short8 wb[4];
#pragma unroll
        for (int nt = 0; nt < 4; ++nt)
            wb[nt] = *(const short8*)(Wb0 + ch * 8192 + nt * 512);

        __syncthreads();               // previous chunk's hs readers done
        union { short s[4]; uint2 u; } pk;
        pk.s[0] = f2bf(hv.x); pk.s[1] = f2bf(hv.y);
        pk.s[2] = f2bf(hv.z); pk.s[3] = f2bf(hv.w);
        *(uint2*)(hs + hrow * 40 + hk) = pk.u;
        __syncthreads();               // hs fully staged

        const short8 a0 = *(const short8*)(hs + c * 40 + q * 8);
        const short8 a1 = *(const short8*)(hs + (16 + c) * 40 + q * 8);
#pragma unroll
        for (int nt = 0; nt < 4; ++nt) {
            acc1[0][nt] = MFMA(a0, wb[nt], acc1[0][nt]);
            acc1[1][nt] = MFMA(a1, wb[nt], acc1[1][nt]);
        }
    }

    // ---------------- bias + LayerNorm (fp32 stats) + exact GELU -----------
    float bb[4], gg[4], ee[4];
#pragma unroll
    for (int nt = 0; nt < 4; ++nt) {
        const int col = w * 64 + nt * 16 + c;
        bb[nt] = b1[col]; gg[nt] = lg[col]; ee[nt] = lb[col];
    }
    float mean[2][4], rstd[2][4];
#pragma unroll
    for (int mt = 0; mt < 2; ++mt)
#pragma unroll
        for (int reg = 0; reg < 4; ++reg) {
            float s1 = 0.f, s2 = 0.f;
#pragma unroll
            for (int nt = 0; nt < 4; ++nt) {
                const float a = acc1[mt][nt][reg] + bb[nt];
                acc1[mt][nt][reg] = a;
                s1 += a; s2 += a * a;
            }
#pragma unroll
            for (int m = 1; m <= 8; m <<= 1) {   // reduce over c (16 lanes)
                s1 += __shfl_xor(s1, m, 64);
                s2 += __shfl_xor(s2, m, 64);
            }
            if (c == 0) {
                const int row = mt * 16 + q * 4 + reg;
                *(float2*)(lnbuf + (w * 32 + row) * 2) = make_float2(s1, s2);
            }
        }
    __syncthreads();
#pragma unroll
    for (int mt = 0; mt < 2; ++mt)
#pragma unroll
        for (int reg = 0; reg < 4; ++reg) {
            const int row = mt * 16 + q * 4 + reg;
            float S1 = 0.f, S2 = 0.f;
#pragma unroll
            for (int w2 = 0; w2 < 4; ++w2) {
                const float2 p = *(const float2*)(lnbuf + (w2 * 32 + row) * 2);
                S1 += p.x; S2 += p.y;
            }
            const float mu = S1 * (1.f / 256.f);
            const float var = S2 * (1.f / 256.f) - mu * mu;
            mean[mt][reg] = mu;
            rstd[mt][reg] = rsqrtf(var + 1e-5f);
        }
#pragma unroll
    for (int mt = 0; mt < 2; ++mt)
#pragma unroll
        for (int reg = 0; reg < 4; ++reg) {
            const int row = mt * 16 + q * 4 + reg;
            const float mu = mean[mt][reg], rs = rstd[mt][reg];
#pragma unroll
            for (int nt = 0; nt < 4; ++nt) {
                const int col = w * 64 + nt * 16 + c;
                const float xv = (acc1[mt][nt][reg] - mu) * rs * gg[nt] + ee[nt];
                const float yv = 0.5f * xv * (1.f + erff(xv * 0.70710678118654752f));
                xs[row * 264 + col] = f2bf(yv);
            }
        }
    __syncthreads();

    // ---------------- GEMM2: m(32x64) = xs(32x256) @ W2(256x64) + b2 -------
    f32x4 acc2[2]; acc2[0] = 0; acc2[1] = 0;
    const short* W2b = W2t + (w * 16 + c) * 256 + q * 8;
#pragma unroll
    for (int ks = 0; ks < 8; ++ks) {
        const short8 xa0 = *(const short8*)(xs + c * 264 + ks * 32 + q * 8);
        const short8 xa1 = *(const short8*)(xs + (16 + c) * 264 + ks * 32 + q * 8);
        const short8 wbk = *(const short8*)(W2b + ks * 32);
        acc2[0] = MFMA(xa0, wbk, acc2[0]);
        acc2[1] = MFMA(xa1, wbk, acc2[1]);
    }
    const float bc = b2[w * 16 + c];
#pragma unroll
    for (int mt = 0; mt < 2; ++mt)
#pragma unroll
        for (int reg = 0; reg < 4; ++reg) {
            const int row = mt * 16 + q * 4 + reg;
            mo[(size_t)(b0 + row) * 64 + w * 16 + c] = f2bf(acc2[mt][reg] + bc);
        }
}

// ---- cliff: Clifford collapse (R1-proven) + readout with T staged in LDS ---
__global__ __launch_bounds__(256, 2)
void cdd_cliff_kernel(const short* __restrict__ mp, const short* __restrict__ mv,
                      const float* __restrict__ T, const float* __restrict__ gw,
                      float* __restrict__ out)
{
    __shared__ __align__(16) float wfl[32 * 68];    // collapsed w, fp32
    __shared__ __align__(16) float ts[95 * 68];     // T staged (pad 68)
    const int t  = threadIdx.x;
    const int b0 = blockIdx.x * 32;

    // stage T: 95 rows x 16 float4
#pragma unroll
    for (int k = 0; k < 6; ++k) {
        const int o = t + k * 256;
        if (o < 95 * 16) {
            const int rr = o >> 4, c4 = (o & 15) << 2;
            *(float4*)(ts + rr * 68 + c4) = *(const float4*)(T + rr * 64 + c4);
        }
    }

    // collapse: w[row][kq*8 .. +8] from mp,mv (fp32 math, bf16 inputs)
    {
        const int row = t >> 3, kq = t & 7;
        float g[8];
#pragma unroll
        for (int i = 0; i < 8; ++i) g[i] = gw[i];
        const short8 p8 = *(const short8*)(mp + (size_t)(b0 + row) * 64 + kq * 8);
        const short8 q8 = *(const short8*)(mv + (size_t)(b0 + row) * 64 + kq * 8);
        float mpv[8], mvv[8];
#pragma unroll
        for (int i = 0; i < 8; ++i) { mpv[i] = bf2f(p8[i]); mvv[i] = bf2f(q8[i]); }

        constexpr int MSK[8] = {0, 1, 2, 4, 3, 5, 6, 7};
        float v[8];
#pragma unroll
        for (int m = 0; m < 8; ++m) {
            float s = 0.f;
#pragma unroll
            for (int j = 0; j < 8; ++j) {
                const int am = MSK[m], bm = MSK[j];
                const int par = (__popc((am >> 1) & bm) + __popc((am >> 2) & bm)) & 1;
                const float sg = par ? -1.f : 1.f;
                s = fmaf(sg * g[MSK[am ^ bm]], mvv[j], s);
            }
            v[m] = s;
        }
#pragma unroll
        for (int l2 = 0; l2 < 8; ++l2) {
            float s = 0.f;
#pragma unroll
            for (int i = 0; i < 8; ++i) {
                const int am = MSK[i], bm = MSK[l2];
                const int par = (__popc((am >> 1) & bm) + __popc((am >> 2) & bm)) & 1;
                const float sg = par ? -1.f : 1.f;
                s = fmaf(sg * mpv[i], v[MSK[am ^ bm]], s);
            }
            wfl[row * 68 + kq * 8 + l2] = s;
        }
    }
    __syncthreads();

    // readout: thread group-of-8 owns one b-row; w row in registers;
    // ts reads: 8 distinct rows x 8-fold broadcast -> conflict-free.
    {
        const int rr = t >> 3, rl = t & 7;
        float4 wv[16];
#pragma unroll
        for (int cc = 0; cc < 16; ++cc)
            wv[cc] = *(const float4*)(wfl + rr * 68 + cc * 4);
#pragma unroll
        for (int k = 0; k < 12; ++k) {
            const int r = rl + (k << 3);
            if (r < R_) {
                float s = 0.f;
#pragma unroll
                for (int cc = 0; cc < 16; ++cc) {
                    const float4 tv = *(const float4*)(ts + r * 68 + cc * 4);
                    s += wv[cc].x * tv.x + wv[cc].y * tv.y
                       + wv[cc].z * tv.z + wv[cc].w * tv.w;
                }
                out[(size_t)(b0 + rr) * R_ + r] = 0.125f * s;
            }
        }
    }
}

extern "C" void kernel_launch(void* const* d_in, const int* in_sizes, int n_in,
                              void* d_out, int out_size, void* d_ws, size_t ws_size,
                              hipStream_t stream)
{
    const float* h_p = (const float*)d_in[0];
    const float* h_v = (const float*)d_in[1];
    const float* Wp1 = (const float*)d_in[2];
    const float* bp1 = (const float*)d_in[3];
    const float* lgp = (const float*)d_in[4];
    const float* lbp = (const float*)d_in[5];
    const float* Wp2 = (const float*)d_in[6];
    const float* bp2 = (const float*)d_in[7];
    const float* Wv1 = (const float*)d_in[8];
    const float* bv1 = (const float*)d_in[9];
    const float* lgv = (const float*)d_in[10];
    const float* lbv = (const float*)d_in[11];
    const float* Wv2 = (const float*)d_in[12];
    const float* bv2 = (const float*)d_in[13];
    const float* T   = (const float*)d_in[14];
    const float* gw  = (const float*)d_in[15];
    float* out = (float*)d_out;

    // ws layout (total 4.78 MB < R1's proven 8.39 MB):
    short* W1c_p = (short*)d_ws;                 // [16][256][32]
    short* W1c_v = W1c_p + 16 * 256 * 32;
    short* W2t_p = W1c_v + 16 * 256 * 32;        // [64][256]
    short* W2t_v = W2t_p + 64 * 256;
    short* mp    = W2t_v + 64 * 256;             // (B,64) bf16
    short* mv    = mp + (size_t)B_ * 64;         // (B,64) bf16

    cdd_prep_kernel<<<512, 256, 0, stream>>>(Wp1, Wv1, Wp2, Wv2,
                                             W1c_p, W1c_v, W2t_p, W2t_v);
    dim3 g1(B_ / 32, 2);
    cdd_proj_kernel<<<g1, 256, 0, stream>>>(h_p, h_v,
                                            bp1, lgp, lbp, bp2,
                                            bv1, lgv, lbv, bv2,
                                            W1c_p, W1c_v, W2t_p, W2t_v,
                                            mp, mv);
    cdd_cliff_kernel<<<B_ / 32, 256, 0, stream>>>(mp, mv, T, gw, out);
}

// Round 7
// 162.640 us; speedup vs baseline: 1.7728x; 1.0020x over previous
//
#include <hip/hip_runtime.h>
#include <math.h>

// CliffordDDIDecoder — R7 = R4 (passed, 163us) + gelu_fast ONLY.
// Bisect round: R2/R3/R5/R6 all failed and all shared the MFMA readout vs
// prep-built Tb in the out-writing kernel (6/6 correlation; both passes R1/R4
// used a VALU-dot readout). Cliff + prep are R4-verbatim; the only delta is
// the A&S 7.1.26 erf GELU (lane-local pure math, abs err 1.5e-7) replacing
// libm erff — R4's #1 VALU consumer in proj (~12us).

#define B_ 16384
#define D_ 512
#define H_ 256
#define R_ 95

typedef __attribute__((ext_vector_type(8))) short short8;   // 8 bf16
typedef __attribute__((ext_vector_type(4))) float f32x4;

#define MFMA(a, b, c) __builtin_amdgcn_mfma_f32_16x16x32_bf16(a, b, c, 0, 0, 0)

__device__ __forceinline__ short f2bf(float x) {            // fp32 -> bf16 RNE
    union { float f; unsigned u; } v; v.f = x;
    unsigned r = v.u + 0x7fffu + ((v.u >> 16) & 1u);
    return (short)(r >> 16);
}
__device__ __forceinline__ float bf2f(short s) {
    union { float f; unsigned u; } v;
    v.u = ((unsigned)(unsigned short)s) << 16;
    return v.f;
}

// exact GELU, erf via Abramowitz-Stegun 7.1.26 (max abs err 1.5e-7 — far
// below the bf16 rounding applied to xs immediately after).
__device__ __forceinline__ float gelu_fast(float x) {
    const float z  = x * 0.70710678118654752f;
    const float az = fabsf(z);
    const float t  = 1.0f / fmaf(0.3275911f, az, 1.0f);
    float p = fmaf(1.061405429f, t, -1.453152027f);
    p = fmaf(p, t, 1.421413741f);
    p = fmaf(p, t, -0.284496736f);
    p = fmaf(p, t, 0.254829592f);
    p *= t;
    const float e  = 1.0f - p * __expf(-az * az);
    const float er = copysignf(e, z);
    return 0.5f * x * (1.0f + er);
}

// ---- prep: W1 -> [16 chunk][256 n][32 k] bf16 ; W2 -> [64 n][256 k] bf16 ----
__global__ __launch_bounds__(256)
void cdd_prep_kernel(const float* __restrict__ Wp1, const float* __restrict__ Wv1,
                     const float* __restrict__ Wp2, const float* __restrict__ Wv2,
                     short* __restrict__ W1c_p, short* __restrict__ W1c_v,
                     short* __restrict__ W2t_p, short* __restrict__ W2t_v)
{
    const int o = blockIdx.x * 256 + threadIdx.x;
    if (o < 16 * 256 * 32) {            // n-fast: coalesced W1 reads
        const int n = o & 255, kin = (o >> 8) & 31, ch = o >> 13;
        const int src = (ch * 32 + kin) * 256 + n;
        const int dst = ch * 8192 + n * 32 + kin;
        W1c_p[dst] = f2bf(Wp1[src]);
        W1c_v[dst] = f2bf(Wv1[src]);
    }
    if (o < 64 * 256) {
        const int n = o >> 8, k = o & 255;
        W2t_p[o] = f2bf(Wp2[k * 64 + n]);
        W2t_v[o] = f2bf(Wv2[k * 64 + n]);
    }
}

// ---- proj: x1=h@W1+b1 -> LN -> exact GELU -> m=x@W2+b2 (bf16 to ws) --------
// grid (512, 2): blockIdx.y picks perp/vuln. R4 body verbatim except gelu_fast.
__global__ __launch_bounds__(256, 2)
void cdd_proj_kernel(const float* __restrict__ h_p, const float* __restrict__ h_v,
                     const float* __restrict__ bp1, const float* __restrict__ lgp,
                     const float* __restrict__ lbp, const float* __restrict__ bp2,
                     const float* __restrict__ bv1, const float* __restrict__ lgv,
                     const float* __restrict__ lbv, const float* __restrict__ bv2,
                     const short* __restrict__ W1c_p, const short* __restrict__ W1c_v,
                     const short* __restrict__ W2t_p, const short* __restrict__ W2t_v,
                     short* __restrict__ mp_out, short* __restrict__ mv_out)
{
    __shared__ __align__(16) short hs[32 * 40];     // h chunk, bf16
    __shared__ __align__(16) short xs[32 * 264];    // gelu(LN(x1)), bf16
    __shared__ __align__(16) float lnbuf[256];      // per-wave LN partials

    const int which = blockIdx.y;
    const float* __restrict__ h   = which ? h_v : h_p;
    const float* __restrict__ b1  = which ? bv1 : bp1;
    const float* __restrict__ lg  = which ? lgv : lgp;
    const float* __restrict__ lb  = which ? lbv : lbp;
    const float* __restrict__ b2  = which ? bv2 : bp2;
    const short* __restrict__ W1c = which ? W1c_v : W1c_p;
    const short* __restrict__ W2t = which ? W2t_v : W2t_p;
    short* __restrict__ mo = which ? mv_out : mp_out;

    const int t = threadIdx.x;
    const int w = t >> 6, l = t & 63, q = l >> 4, c = l & 15;
    const int b0 = blockIdx.x * 32;
    const int hrow = t >> 3, hk = (t & 7) * 4;     // h staging map

    // ---------------- GEMM1: acc1[mt][nt] = h(32x512) @ W1(512x256) --------
    f32x4 acc1[2][4];
#pragma unroll
    for (int mt = 0; mt < 2; ++mt)
#pragma unroll
        for (int nt = 0; nt < 4; ++nt) acc1[mt][nt] = 0;

    const size_t hoff = (size_t)(b0 + hrow) * D_ + hk;
    const short* Wb0 = W1c + (w * 64 + c) * 32 + q * 8;

    for (int ch = 0; ch < 16; ++ch) {
        const float4 hv = *(const float4*)(h + hoff + ch * 32);
        short8 wb[4];
#pragma unroll
        for (int nt = 0; nt < 4; ++nt)
            wb[nt] = *(const short8*)(Wb0 + ch * 8192 + nt * 512);

        __syncthreads();               // previous chunk's hs readers done
        union { short s[4]; uint2 u; } pk;
        pk.s[0] = f2bf(hv.x); pk.s[1] = f2bf(hv.y);
        pk.s[2] = f2bf(hv.z); pk.s[3] = f2bf(hv.w);
        *(uint2*)(hs + hrow * 40 + hk) = pk.u;
        __syncthreads();               // hs fully staged

        const short8 a0 = *(const short8*)(hs + c * 40 + q * 8);
        const short8 a1 = *(const short8*)(hs + (16 + c) * 40 + q * 8);
#pragma unroll
        for (int nt = 0; nt < 4; ++nt) {
            acc1[0][nt] = MFMA(a0, wb[nt], acc1[0][nt]);
            acc1[1][nt] = MFMA(a1, wb[nt], acc1[1][nt]);
        }
    }

    // ---------------- bias + LayerNorm (fp32 stats) + fast exact GELU ------
    float bb[4], gg[4], ee[4];
#pragma unroll
    for (int nt = 0; nt < 4; ++nt) {
        const int col = w * 64 + nt * 16 + c;
        bb[nt] = b1[col]; gg[nt] = lg[col]; ee[nt] = lb[col];
    }
    float mean[2][4], rstd[2][4];
#pragma unroll
    for (int mt = 0; mt < 2; ++mt)
#pragma unroll
        for (int reg = 0; reg < 4; ++reg) {
            float s1 = 0.f, s2 = 0.f;
#pragma unroll
            for (int nt = 0; nt < 4; ++nt) {
                const float a = acc1[mt][nt][reg] + bb[nt];
                acc1[mt][nt][reg] = a;
                s1 += a; s2 += a * a;
            }
#pragma unroll
            for (int m = 1; m <= 8; m <<= 1) {   // reduce over c (16 lanes)
                s1 += __shfl_xor(s1, m, 64);
                s2 += __shfl_xor(s2, m, 64);
            }
            if (c == 0) {
                const int row = mt * 16 + q * 4 + reg;
                *(float2*)(lnbuf + (w * 32 + row) * 2) = make_float2(s1, s2);
            }
        }
    __syncthreads();
#pragma unroll
    for (int mt = 0; mt < 2; ++mt)
#pragma unroll
        for (int reg = 0; reg < 4; ++reg) {
            const int row = mt * 16 + q * 4 + reg;
            float S1 = 0.f, S2 = 0.f;
#pragma unroll
            for (int w2 = 0; w2 < 4; ++w2) {
                const float2 p = *(const float2*)(lnbuf + (w2 * 32 + row) * 2);
                S1 += p.x; S2 += p.y;
            }
            const float mu = S1 * (1.f / 256.f);
            const float var = S2 * (1.f / 256.f) - mu * mu;
            mean[mt][reg] = mu;
            rstd[mt][reg] = rsqrtf(var + 1e-5f);
        }
#pragma unroll
    for (int mt = 0; mt < 2; ++mt)
#pragma unroll
        for (int reg = 0; reg < 4; ++reg) {
            const int row = mt * 16 + q * 4 + reg;
            const float mu = mean[mt][reg], rs = rstd[mt][reg];
#pragma unroll
            for (int nt = 0; nt < 4; ++nt) {
                const int col = w * 64 + nt * 16 + c;
                const float xv = (acc1[mt][nt][reg] - mu) * rs * gg[nt] + ee[nt];
                xs[row * 264 + col] = f2bf(gelu_fast(xv));
            }
        }
    __syncthreads();

    // ---------------- GEMM2: m(32x64) = xs(32x256) @ W2(256x64) + b2 -------
    f32x4 acc2[2]; acc2[0] = 0; acc2[1] = 0;
    const short* W2b = W2t + (w * 16 + c) * 256 + q * 8;
#pragma unroll
    for (int ks = 0; ks < 8; ++ks) {
        const short8 xa0 = *(const short8*)(xs + c * 264 + ks * 32 + q * 8);
        const short8 xa1 = *(const short8*)(xs + (16 + c) * 264 + ks * 32 + q * 8);
        const short8 wbk = *(const short8*)(W2b + ks * 32);
        acc2[0] = MFMA(xa0, wbk, acc2[0]);
        acc2[1] = MFMA(xa1, wbk, acc2[1]);
    }
    const float bc = b2[w * 16 + c];
#pragma unroll
    for (int mt = 0; mt < 2; ++mt)
#pragma unroll
        for (int reg = 0; reg < 4; ++reg) {
            const int row = mt * 16 + q * 4 + reg;
            mo[(size_t)(b0 + row) * 64 + w * 16 + c] = f2bf(acc2[mt][reg] + bc);
        }
}

// ---- cliff: R4-verbatim — Clifford collapse + VALU-dot readout, T in LDS ---
__global__ __launch_bounds__(256, 2)
void cdd_cliff_kernel(const short* __restrict__ mp, const short* __restrict__ mv,
                      const float* __restrict__ T, const float* __restrict__ gw,
                      float* __restrict__ out)
{
    __shared__ __align__(16) float wfl[32 * 68];    // collapsed w, fp32
    __shared__ __align__(16) float ts[95 * 68];     // T staged (pad 68)
    const int t  = threadIdx.x;
    const int b0 = blockIdx.x * 32;

    // stage T: 95 rows x 16 float4
#pragma unroll
    for (int k = 0; k < 6; ++k) {
        const int o = t + k * 256;
        if (o < 95 * 16) {
            const int rr = o >> 4, c4 = (o & 15) << 2;
            *(float4*)(ts + rr * 68 + c4) = *(const float4*)(T + rr * 64 + c4);
        }
    }

    // collapse: w[row][kq*8 .. +8] from mp,mv (fp32 math, bf16 inputs)
    {
        const int row = t >> 3, kq = t & 7;
        float g[8];
#pragma unroll
        for (int i = 0; i < 8; ++i) g[i] = gw[i];
        const short8 p8 = *(const short8*)(mp + (size_t)(b0 + row) * 64 + kq * 8);
        const short8 q8 = *(const short8*)(mv + (size_t)(b0 + row) * 64 + kq * 8);
        float mpv[8], mvv[8];
#pragma unroll
        for (int i = 0; i < 8; ++i) { mpv[i] = bf2f(p8[i]); mvv[i] = bf2f(q8[i]); }

        constexpr int MSK[8] = {0, 1, 2, 4, 3, 5, 6, 7};
        float v[8];
#pragma unroll
        for (int m = 0; m < 8; ++m) {
            float s = 0.f;
#pragma unroll
            for (int j = 0; j < 8; ++j) {
                const int am = MSK[m], bm = MSK[j];
                const int par = (__popc((am >> 1) & bm) + __popc((am >> 2) & bm)) & 1;
                const float sg = par ? -1.f : 1.f;
                s = fmaf(sg * g[MSK[am ^ bm]], mvv[j], s);
            }
            v[m] = s;
        }
#pragma unroll
        for (int l2 = 0; l2 < 8; ++l2) {
            float s = 0.f;
#pragma unroll
            for (int i = 0; i < 8; ++i) {
                const int am = MSK[i], bm = MSK[l2];
                const int par = (__popc((am >> 1) & bm) + __popc((am >> 2) & bm)) & 1;
                const float sg = par ? -1.f : 1.f;
                s = fmaf(sg * mpv[i], v[MSK[am ^ bm]], s);
            }
            wfl[row * 68 + kq * 8 + l2] = s;
        }
    }
    __syncthreads();

    // readout: thread group-of-8 owns one b-row; w row in registers;
    // ts reads: 8 distinct rows x 8-fold broadcast -> conflict-free.
    {
        const int rr = t >> 3, rl = t & 7;
        float4 wv[16];
#pragma unroll
        for (int cc = 0; cc < 16; ++cc)
            wv[cc] = *(const float4*)(wfl + rr * 68 + cc * 4);
#pragma unroll
        for (int k = 0; k < 12; ++k) {
            const int r = rl + (k << 3);
            if (r < R_) {
                float s = 0.f;
#pragma unroll
                for (int cc = 0; cc < 16; ++cc) {
                    const float4 tv = *(const float4*)(ts + r * 68 + cc * 4);
                    s += wv[cc].x * tv.x + wv[cc].y * tv.y
                       + wv[cc].z * tv.z + wv[cc].w * tv.w;
                }
                out[(size_t)(b0 + rr) * R_ + r] = 0.125f * s;
            }
        }
    }
}

extern "C" void kernel_launch(void* const* d_in, const int* in_sizes, int n_in,
                              void* d_out, int out_size, void* d_ws, size_t ws_size,
                              hipStream_t stream)
{
    const float* h_p = (const float*)d_in[0];
    const float* h_v = (const float*)d_in[1];
    const float* Wp1 = (const float*)d_in[2];
    const float* bp1 = (const float*)d_in[3];
    const float* lgp = (const float*)d_in[4];
    const float* lbp = (const float*)d_in[5];
    const float* Wp2 = (const float*)d_in[6];
    const float* bp2 = (const float*)d_in[7];
    const float* Wv1 = (const float*)d_in[8];
    const float* bv1 = (const float*)d_in[9];
    const float* lgv = (const float*)d_in[10];
    const float* lbv = (const float*)d_in[11];
    const float* Wv2 = (const float*)d_in[12];
    const float* bv2 = (const float*)d_in[13];
    const float* T   = (const float*)d_in[14];
    const float* gw  = (const float*)d_in[15];
    float* out = (float*)d_out;

    // ws layout (4.78 MB), R4-verbatim:
    short* W1c_p = (short*)d_ws;                 // [16][256][32]
    short* W1c_v = W1c_p + 16 * 256 * 32;
    short* W2t_p = W1c_v + 16 * 256 * 32;        // [64][256]
    short* W2t_v = W2t_p + 64 * 256;
    short* mp    = W2t_v + 64 * 256;             // (B,64) bf16
    short* mv    = mp + (size_t)B_ * 64;         // (B,64) bf16

    cdd_prep_kernel<<<512, 256, 0, stream>>>(Wp1, Wv1, Wp2, Wv2,
                                             W1c_p, W1c_v, W2t_p, W2t_v);
    dim3 g1(B_ / 32, 2);
    cdd_proj_kernel<<<g1, 256, 0, stream>>>(h_p, h_v,
                                            bp1, lgp, lbp, bp2,
                                            bv1, lgv, lbv, bv2,
                                            W1c_p, W1c_v, W2t_p, W2t_v,
                                            mp, mv);
    cdd_cliff_kernel<<<B_ / 32, 256, 0, stream>>>(mp, mv, T, gw, out);
}